// Round 23
// baseline (79.425 us; speedup 1.0000x reference)
//
#include <hip/hip_runtime.h>
#include <hip/hip_fp16.h>

#define B_ 64
#define N_ 4096
#define C_ 10
#define D_ 8
#define E_ 16
#define EPS_ 1e-7f
#define NT_ 8
#define NBLK_ (N_ / NT_)          // 512 pass blocks
#define NSLOT_ NBLK_              // 512 partial slots (1 per block)
#define PROW_ 80                  // u32 per partial row (160 halfs)
#define WBROW_ 82                 // padded LDS combine row stride (u32)
#define NSG_ 8                    // reduce stage-A slot groups

typedef _Float16 h2_t __attribute__((ext_vector_type(2)));
typedef __fp16   p2_t __attribute__((ext_vector_type(2)));   // cvt_pkrtz ret type

__device__ inline unsigned pkh(float a, float b) {   // f32x2 -> packed fp16
    p2_t t = __builtin_amdgcn_cvt_pkrtz(a, b);
    return *(unsigned*)&t;
}
#if __has_builtin(__builtin_amdgcn_fdot2)
__device__ inline float fd2(unsigned a, unsigned b, float c) {
    h2_t av = *(h2_t*)&a, bv = *(h2_t*)&b;
    return __builtin_amdgcn_fdot2(av, bv, c, false);
}
#else
__device__ inline float fd2(unsigned a, unsigned b, float c) {
    h2_t av = *(h2_t*)&a, bv = *(h2_t*)&b;
    return fmaf((float)av.x, (float)bv.x, fmaf((float)av.y, (float)bv.y, c));
}
#endif
__device__ inline float hlo(unsigned u) { h2_t t = *(h2_t*)&u; return (float)t.x; }
__device__ inline float hhi(unsigned u) { h2_t t = *(h2_t*)&u; return (float)t.y; }
__device__ inline unsigned hpack(float a, float b) {
    __half2 t = __floats2half2_rn(a, b);
    return *(unsigned*)&t;
}
__device__ inline float2 hunpack(unsigned u) {
    return __half22float2(*(const __half2*)&u);
}

// Block: 256 thr = 4 waves = (cg: c-half) x (np: n-half). Thread owns FOUR b
// (b = bl + i*16, i=0..3) and FIVE c: each W ds_read_b128 feeds 32 fd2 ->
// per-CU LDS-read issues HALVED vs R22 (the dominant pipe). ~216 VGPR live
// set under the 256 cap of launch_bounds(256,2) (R12 precedent: no spill).
// Exp-sum exchange: float4 (4 b's) between cg-partner waves, dbuf by j&1.
template <bool UNIFORM>
__global__ __launch_bounds__(256, 2) void caps_pass(
    const float* __restrict__ x, const float* __restrict__ W,
    const unsigned* __restrict__ vpk, unsigned* __restrict__ partial)
{
    __shared__ __align__(16) char smem[30720];
    uint4*    wlds = (uint4*)smem;                   // 1280 uint4 = 20480 B
    unsigned* xlds = (unsigned*)(smem + 20480);      // 2048 u32  =  8192 B
    float*    xch  = (float*)(smem + 28672);         // 512 f32   =  2048 B
    unsigned* wb   = (unsigned*)smem;                // combine alias (20992 B)

    const int tid = (int)threadIdx.x;
    const int blk = (int)blockIdx.x;
    const int n0  = blk * NT_;

    // ---- stage W -> LDS fp16 d-pair granules [n][c][d2][eq] ----
    {
        const float4* wg = (const float4*)W + (size_t)blk * (NT_ * 320);
#pragma unroll
        for (int k = 0; k < 5; ++k) {
            const int g = k * 256 + tid;          // [0, 1280)
            const int n   = g / 160;
            const int rem = g - n * 160;
            const int c   = rem >> 4;
            const int r2  = rem & 15;
            const int d2  = r2 >> 2;
            const int eqs = r2 & 3;
            const float4 g0 = wg[n * 320 + c * 32 + (2 * d2) * 4 + eqs];
            const float4 g1 = wg[n * 320 + c * 32 + (2 * d2 + 1) * 4 + eqs];
            wlds[((n * C_ + c) * 4 + d2) * 4 + eqs] =
                make_uint4(pkh(g0.x, g1.x), pkh(g0.y, g1.y),
                           pkh(g0.z, g1.z), pkh(g0.w, g1.w));
        }
    }
    // ---- stage x -> LDS fp16 d-pair words [n][b][4] ----
    {
        const float4* xg = (const float4*)x;
#pragma unroll
        for (int k = 0; k < 4; ++k) {
            const int g = k * 256 + tid;          // [0, 1024)
            const int b = g >> 4;
            const int r = g & 15;
            const int n = r >> 1;
            const int dq = r & 1;
            const float4 v = xg[((size_t)b * N_ + n0 + n) * 2 + dq];
            *(uint2*)&xlds[(n * B_ + b) * 4 + dq * 2] =
                make_uint2(pkh(v.x, v.y), pkh(v.z, v.w));
        }
    }
    __syncthreads();

    const int wv   = tid >> 6;
    const int lane = tid & 63;
    const int eq   = lane & 3;
    const int bl   = lane >> 2;        // 0..15
    const int cg   = wv & 1;           // c-half: 0 -> c 0..4, 1 -> c 5..9
    const int np   = wv >> 1;          // n-half: 4 n each
    const int cbase = cg * 5;
    // b[i] = bl + i*16

    unsigned vcp[4][5][2];
    if (!UNIFORM) {
#pragma unroll
        for (int i = 0; i < 4; ++i) {
            const int b = bl + i * 16;
#pragma unroll
            for (int cc = 0; cc < 5; ++cc) {
                const uint2 a = *(const uint2*)(vpk + (b * C_ + cbase + cc) * 8 + eq * 2);
                vcp[i][cc][0] = a.x; vcp[i][cc][1] = a.y;
            }
        }
    }

    float4 acc[4][5];
#pragma unroll
    for (int i = 0; i < 4; ++i)
#pragma unroll
        for (int cc = 0; cc < 5; ++cc)
            acc[i][cc] = make_float4(0.f, 0.f, 0.f, 0.f);

#pragma unroll 1
    for (int j = 0; j < 4; ++j) {
        const int nl = np * 4 + j;
        unsigned xa[4][4];
#pragma unroll
        for (int i = 0; i < 4; ++i) {
            const uint4 xq = *(const uint4*)&xlds[(nl * B_ + bl + i * 16) * 4];
            xa[i][0] = xq.x; xa[i][1] = xq.y; xa[i][2] = xq.z; xa[i][3] = xq.w;
        }

        if (UNIFORM) {
#pragma unroll
            for (int cc = 0; cc < 5; ++cc) {
                const uint4* wq = &wlds[(nl * C_ + cbase + cc) * 16];
#pragma unroll
                for (int d2 = 0; d2 < 4; ++d2) {
                    const uint4 q = wq[d2 * 4 + eq];
#pragma unroll
                    for (int i = 0; i < 4; ++i) {
                        acc[i][cc].x = fd2(xa[i][d2], q.x, acc[i][cc].x);
                        acc[i][cc].y = fd2(xa[i][d2], q.y, acc[i][cc].y);
                        acc[i][cc].z = fd2(xa[i][d2], q.z, acc[i][cc].z);
                        acc[i][cc].w = fd2(xa[i][d2], q.w, acc[i][cc].w);
                    }
                }
            }
        } else {
            unsigned uhp[4][5][2];
            float wgt[4][5];
            float s[4] = {0.f, 0.f, 0.f, 0.f};
#pragma unroll
            for (int cc = 0; cc < 5; ++cc) {
                const uint4* wq = &wlds[(nl * C_ + cbase + cc) * 16];
                float4 u[4];
#pragma unroll
                for (int i = 0; i < 4; ++i) u[i] = make_float4(0.f, 0.f, 0.f, 0.f);
#pragma unroll
                for (int d2 = 0; d2 < 4; ++d2) {
                    const uint4 q = wq[d2 * 4 + eq];
#pragma unroll
                    for (int i = 0; i < 4; ++i) {
                        u[i].x = fd2(xa[i][d2], q.x, u[i].x);
                        u[i].y = fd2(xa[i][d2], q.y, u[i].y);
                        u[i].z = fd2(xa[i][d2], q.z, u[i].z);
                        u[i].w = fd2(xa[i][d2], q.w, u[i].w);
                    }
                }
#pragma unroll
                for (int i = 0; i < 4; ++i) {
                    const unsigned up0 = pkh(u[i].x, u[i].y);
                    const unsigned up1 = pkh(u[i].z, u[i].w);
                    float t = fd2(up0, vcp[i][cc][0], fd2(up1, vcp[i][cc][1], 0.f));
                    t += __shfl_xor(t, 1); t += __shfl_xor(t, 2);
                    const float e = __expf(t);
                    wgt[i][cc] = e; s[i] += e;
                    uhp[i][cc][0] = up0; uhp[i][cc][1] = up1;
                }
            }
            // exchange 5-class exp-sums with the cg-partner wave (same np, bl)
            float* xme = xch + ((((j & 1) * 2 + cg) * 2 + np) * 16 + bl) * 4;
            const float* xot = xch + ((((j & 1) * 2 + (cg ^ 1)) * 2 + np) * 16 + bl) * 4;
            if (eq == 0) *(float4*)xme = make_float4(s[0], s[1], s[2], s[3]);
            __syncthreads();
#pragma unroll
            for (int i = 0; i < 4; ++i) {
                const float inv = 1.f / (s[i] + xot[i]);
#pragma unroll
                for (int cc = 0; cc < 5; ++cc) {
                    const float g = wgt[i][cc] * inv;
                    acc[i][cc].x = fmaf(g, hlo(uhp[i][cc][0]), acc[i][cc].x);
                    acc[i][cc].y = fmaf(g, hhi(uhp[i][cc][0]), acc[i][cc].y);
                    acc[i][cc].z = fmaf(g, hlo(uhp[i][cc][1]), acc[i][cc].z);
                    acc[i][cc].w = fmaf(g, hhi(uhp[i][cc][1]), acc[i][cc].w);
                }
            }
        }
    }

    // ---- combine np halves via fp16 LDS (alias over dead W/x) ----
    const float fold = UNIFORM ? 0.1f : 1.f;   // softmax(0) = 1/10 folded out
    __syncthreads();   // all wlds/xlds reads done; smem becomes wb
    if (np == 1) {
#pragma unroll
        for (int i = 0; i < 4; ++i) {
            const int b = bl + i * 16;
#pragma unroll
            for (int cc = 0; cc < 5; ++cc) {
                const int c = cbase + cc;
                *(uint2*)&wb[b * WBROW_ + c * 8 + eq * 2] =
                    make_uint2(hpack(acc[i][cc].x * fold, acc[i][cc].y * fold),
                               hpack(acc[i][cc].z * fold, acc[i][cc].w * fold));
            }
        }
    }
    __syncthreads();
    if (np == 0) {
#pragma unroll
        for (int i = 0; i < 4; ++i) {
            const int b = bl + i * 16;
#pragma unroll
            for (int cc = 0; cc < 5; ++cc) {
                const int c = cbase + cc;
                const uint2 p0 = *(const uint2*)&wb[b * WBROW_ + c * 8 + eq * 2];
                const float2 a0 = hunpack(p0.x), a1 = hunpack(p0.y);
                *(uint2*)(partial + ((size_t)b * NSLOT_ + blk) * PROW_ + c * 8 + eq * 2) =
                    make_uint2(hpack(a0.x + acc[i][cc].x * fold, a0.y + acc[i][cc].y * fold),
                               hpack(a1.x + acc[i][cc].z * fold, a1.y + acc[i][cc].w * fold));
            }
        }
    }
}

// Reduce stage A: 512 blocks = (b, sg); sum 64 slots -> sub[b][sg][160] f32.
__global__ __launch_bounds__(256) void caps_redA(
    const unsigned* __restrict__ partial, float* __restrict__ sub)
{
    const int b  = (int)blockIdx.x >> 3;
    const int sg = (int)blockIdx.x & 7;
    const int tid = (int)threadIdx.x;
    const int sc   = tid >> 5;          // 0..7
    const int col4 = tid & 31;          // active < 20
    __shared__ float red[8][20][8];
    if (col4 < 20) {
        float s[8];
#pragma unroll
        for (int p = 0; p < 8; ++p) s[p] = 0.f;
        const int slot0 = sg * (NSLOT_ / NSG_) + sc * 8;
        const uint4* base = (const uint4*)(partial +
            ((size_t)b * NSLOT_ + slot0) * PROW_) + col4;
#pragma unroll 4
        for (int k = 0; k < 8; ++k) {
            const uint4 q = base[k * (PROW_ / 4)];
            const float2 f0 = hunpack(q.x), f1 = hunpack(q.y);
            const float2 f2 = hunpack(q.z), f3 = hunpack(q.w);
            s[0] += f0.x; s[1] += f0.y; s[2] += f1.x; s[3] += f1.y;
            s[4] += f2.x; s[5] += f2.y; s[6] += f3.x; s[7] += f3.y;
        }
#pragma unroll
        for (int p = 0; p < 8; ++p) red[sc][col4][p] = s[p];
    }
    __syncthreads();
    if (tid < 160) {
        const int c4 = tid >> 3, p = tid & 7;
        float s = 0.f;
#pragma unroll
        for (int ch = 0; ch < 8; ++ch) s += red[ch][c4][p];
        sub[((size_t)b * NSG_ + sg) * (C_ * E_) + c4 * 8 + p] = s;
    }
}

// Reduce stage B: 64 blocks x 128 thr; 80 active pair-threads per b.
// Writes f32 v_cum AND packed-fp16 vpk in the pass's vcp word order.
// mode: 0 = v_cum = v, 1 = v_cum += v, 2 = out = v
__global__ __launch_bounds__(128) void caps_redB(
    const float* __restrict__ sub, float* __restrict__ v_cum,
    unsigned* __restrict__ vpk, float* __restrict__ out, int mode)
{
    const int b = (int)blockIdx.x;
    const int tid = (int)threadIdx.x;
    if (tid >= PROW_) return;
    float slo = 0.f, shi = 0.f;
#pragma unroll
    for (int sg = 0; sg < NSG_; ++sg) {
        const float* p = sub + ((size_t)b * NSG_ + sg) * (C_ * E_) + tid * 2;
        slo += p[0]; shi += p[1];
    }
    float p = slo * slo + shi * shi;     // sum over the 16 e of this c
    p += __shfl_xor(p, 1); p += __shfl_xor(p, 2); p += __shfl_xor(p, 4);
    const float sc = (p / (1.f + p)) * rsqrtf(p + EPS_);
    float v0 = sc * slo, v1 = sc * shi;
    const int o = b * (C_ * E_) + tid * 2;
    if (mode == 2) {
        out[o] = v0; out[o + 1] = v1;
    } else {
        if (mode == 0) {
            v_cum[o] = v0; v_cum[o + 1] = v1;
        } else {
            v0 += v_cum[o]; v1 += v_cum[o + 1];
            v_cum[o] = v0; v_cum[o + 1] = v1;
        }
        vpk[b * PROW_ + tid] = hpack(v0, v1);
    }
}

extern "C" void kernel_launch(void* const* d_in, const int* in_sizes, int n_in,
                              void* d_out, int out_size, void* d_ws, size_t ws_size,
                              hipStream_t stream) {
    const float* x = (const float*)d_in[0];
    const float* W = (const float*)d_in[1];
    float* out = (float*)d_out;

    // ws: partial 10.49 MB | sub 327 KB | v_cum 40 KB | vpk 20 KB
    char* p = (char*)d_ws;
    unsigned* partial = (unsigned*)p;
    p += (size_t)B_ * NSLOT_ * PROW_ * sizeof(unsigned);
    float* sub = (float*)p;
    p += (size_t)B_ * NSG_ * C_ * E_ * sizeof(float);
    float* v_cum = (float*)p;
    p += (size_t)B_ * C_ * E_ * sizeof(float);
    unsigned* vpk = (unsigned*)p;

    for (int t = 0; t < 3; ++t) {
        if (t == 0)
            caps_pass<true ><<<dim3(NBLK_), 256, 0, stream>>>(x, W, vpk, partial);
        else
            caps_pass<false><<<dim3(NBLK_), 256, 0, stream>>>(x, W, vpk, partial);
        caps_redA<<<dim3(B_ * NSG_), 256, 0, stream>>>(partial, sub);
        caps_redB<<<dim3(B_), 128, 0, stream>>>(sub, v_cum, vpk, out, t);
    }
}